// Round 1
// baseline (1639.306 us; speedup 1.0000x reference)
//
#include <hip/hip_runtime.h>
#include <cstdint>
#include <cstddef>

#define BB 128
#define NN 300
#define EE 300
#define DIN 768
#define DH 256
#define NREL 26
#define NHEADS 8
#define HDIM 32
#define MTOT (BB*NN)    // 38400
#define NEDGE (BB*EE)   // 38400

// ---------------- edge bucketing by relation ----------------
__global__ void k0_zero(int* __restrict__ cnt, int* __restrict__ cur) {
    int i = threadIdx.x;
    if (i < NREL) { cnt[i] = 0; cur[i] = 0; }
}

__global__ void k0_count(const int* __restrict__ etype, int* __restrict__ cnt) {
    int i = blockIdx.x * 256 + threadIdx.x;
    if (i < NEDGE) atomicAdd(&cnt[etype[i]], 1);
}

__global__ void k0_scan(const int* __restrict__ cnt, int* __restrict__ off) {
    if (threadIdx.x == 0) {
        int acc = 0;
        for (int r = 0; r < NREL; ++r) { off[r] = acc; acc += cnt[r]; }
        off[NREL] = acc;
    }
}

__global__ void k0_fill(const int* __restrict__ etype, const int* __restrict__ off,
                        int* __restrict__ cur, int* __restrict__ list) {
    int i = blockIdx.x * 256 + threadIdx.x;
    if (i < NEDGE) {
        int r = etype[i];
        int p = atomicAdd(&cur[r], 1);
        list[off[r] + p] = i;
    }
}

// ---------------- h = x @ W_loop + b_rel  (M=38400,K=768,N=256) ----------------
__global__ __launch_bounds__(256) void k1_selfloop(
    const float* __restrict__ x, const float* __restrict__ wl,
    const float* __restrict__ brel, float* __restrict__ h)
{
    __shared__ float As[64][17];
    __shared__ float Bs[16][64];
    const int m0 = blockIdx.x * 64, n0 = blockIdx.y * 64;
    const int tid = threadIdx.x;
    const int ty = tid >> 4, tx = tid & 15;
    const int lr = tid >> 2, lk = (tid & 3) * 4;   // A stage
    float acc[4][4] = {};
    for (int kt = 0; kt < DIN; kt += 16) {
        float4 av = *(const float4*)&x[(size_t)(m0 + lr) * DIN + kt + lk];
        As[lr][lk+0] = av.x; As[lr][lk+1] = av.y; As[lr][lk+2] = av.z; As[lr][lk+3] = av.w;
        *(float4*)&Bs[ty][tx*4] = *(const float4*)&wl[(size_t)(kt + ty) * DH + n0 + tx*4];
        __syncthreads();
        #pragma unroll
        for (int k = 0; k < 16; ++k) {
            float4 b4 = *(const float4*)&Bs[k][tx*4];
            #pragma unroll
            for (int i = 0; i < 4; ++i) {
                float a = As[ty*4+i][k];
                acc[i][0] += a * b4.x; acc[i][1] += a * b4.y;
                acc[i][2] += a * b4.z; acc[i][3] += a * b4.w;
            }
        }
        __syncthreads();
    }
    float4 bias = *(const float4*)&brel[n0 + tx*4];
    #pragma unroll
    for (int i = 0; i < 4; ++i) {
        float4 o;
        o.x = acc[i][0] + bias.x; o.y = acc[i][1] + bias.y;
        o.z = acc[i][2] + bias.z; o.w = acc[i][3] + bias.w;
        *(float4*)&h[(size_t)(m0 + ty*4 + i) * DH + n0 + tx*4] = o;
    }
}

// ------- per-relation msg GEMM + scatter-add: h[dst] += x[src] @ W_rel[r] -------
__global__ __launch_bounds__(256) void k2_relmsg(
    const float* __restrict__ x, const float* __restrict__ wrel,
    const int* __restrict__ src, const int* __restrict__ dst,
    const int* __restrict__ cnt, const int* __restrict__ off,
    const int* __restrict__ list, float* __restrict__ h)
{
    __shared__ float As[64][17];
    __shared__ float Bs[16][256];
    __shared__ int arow[64];
    __shared__ int drow[64];
    const int r = blockIdx.y;
    const int c_total = cnt[r];
    const int t0 = blockIdx.x * 64;
    if (t0 >= c_total) return;
    const int tid = threadIdx.x;
    if (tid < 64) {
        int e = t0 + tid;
        if (e < c_total) {
            int eid = list[off[r] + e];
            int b = eid / EE;
            arow[tid] = b * NN + src[eid];
            drow[tid] = b * NN + dst[eid];
        } else { arow[tid] = -1; drow[tid] = -1; }
    }
    __syncthreads();
    const float* wr = wrel + (size_t)r * DIN * DH;
    const int g = tid >> 4, cc = tid & 15;        // compute: rows 4g..4g+3, cols cc+16j
    const int lr = tid >> 2, lk = (tid & 3) * 4;  // A stage
    const int bk = tid >> 4, bc = (tid & 15) * 16; // B stage
    const int ar = arow[lr];
    float acc[4][16] = {};
    for (int kt = 0; kt < DIN; kt += 16) {
        float4 av = make_float4(0.f, 0.f, 0.f, 0.f);
        if (ar >= 0) av = *(const float4*)&x[(size_t)ar * DIN + kt + lk];
        As[lr][lk+0] = av.x; As[lr][lk+1] = av.y; As[lr][lk+2] = av.z; As[lr][lk+3] = av.w;
        #pragma unroll
        for (int q = 0; q < 4; ++q)
            *(float4*)&Bs[bk][bc + 4*q] = *(const float4*)&wr[(size_t)(kt + bk) * DH + bc + 4*q];
        __syncthreads();
        #pragma unroll
        for (int k = 0; k < 16; ++k) {
            float a_[4];
            #pragma unroll
            for (int i = 0; i < 4; ++i) a_[i] = As[4*g+i][k];
            #pragma unroll
            for (int j = 0; j < 16; ++j) {
                float bv = Bs[k][cc + 16*j];
                #pragma unroll
                for (int i = 0; i < 4; ++i) acc[i][j] += a_[i] * bv;
            }
        }
        __syncthreads();
    }
    #pragma unroll
    for (int i = 0; i < 4; ++i) {
        int dr = drow[4*g+i];
        if (dr >= 0) {
            #pragma unroll
            for (int j = 0; j < 16; ++j)
                atomicAdd(&h[(size_t)dr * DH + cc + 16*j], acc[i][j]);
        }
    }
}

// ---------------- qkv = h @ in_proj_w^T + in_proj_b (M=38400,K=256,N=768) ----------------
__global__ __launch_bounds__(256) void k3_qkv(
    const float* __restrict__ h, const float* __restrict__ wq,
    const float* __restrict__ bq, float* __restrict__ qkv)
{
    __shared__ float As[64][17];
    __shared__ float Bs[16][68];
    const int m0 = blockIdx.x * 64, j0 = blockIdx.y * 64;
    const int tid = threadIdx.x;
    const int ty = tid >> 4, tx = tid & 15;
    const int lr = tid >> 2, lk = (tid & 3) * 4;
    float acc[4][4] = {};
    for (int kt = 0; kt < DH; kt += 16) {
        float4 av = *(const float4*)&h[(size_t)(m0 + lr) * DH + kt + lk];
        As[lr][lk+0] = av.x; As[lr][lk+1] = av.y; As[lr][lk+2] = av.z; As[lr][lk+3] = av.w;
        // B transpose-stage: Bs[k][j] = wq[(j0+j)*DH + kt+k]
        float4 wv = *(const float4*)&wq[(size_t)(j0 + lr) * DH + kt + lk];
        Bs[lk+0][lr] = wv.x; Bs[lk+1][lr] = wv.y; Bs[lk+2][lr] = wv.z; Bs[lk+3][lr] = wv.w;
        __syncthreads();
        #pragma unroll
        for (int k = 0; k < 16; ++k) {
            float4 b4 = *(const float4*)&Bs[k][tx*4];
            #pragma unroll
            for (int i = 0; i < 4; ++i) {
                float a = As[ty*4+i][k];
                acc[i][0] += a * b4.x; acc[i][1] += a * b4.y;
                acc[i][2] += a * b4.z; acc[i][3] += a * b4.w;
            }
        }
        __syncthreads();
    }
    float4 bias = *(const float4*)&bq[j0 + tx*4];
    #pragma unroll
    for (int i = 0; i < 4; ++i) {
        float4 o;
        o.x = acc[i][0] + bias.x; o.y = acc[i][1] + bias.y;
        o.z = acc[i][2] + bias.z; o.w = acc[i][3] + bias.w;
        *(float4*)&qkv[(size_t)(m0 + ty*4 + i) * (3*DH) + j0 + tx*4] = o;
    }
}

// ------- flash attention per (b,head) + fused mean-pool accumulation -------
// 512 thr = 8 waves; lane = (rk,c): rk=row-in-group, c=dim-quad. Wave w owns rows {w, w+8, ...}
__global__ __launch_bounds__(512) void k4_attn(
    const float* __restrict__ qkv, float* __restrict__ pooled)
{
    __shared__ float kt_s[64][36];
    __shared__ float vt_s[64][36];
    __shared__ float pool_lds[8][32];
    const int bh = blockIdx.x;
    const int b = bh >> 3, hh = bh & 7;
    const int tid = threadIdx.x;
    const int w = tid >> 6;
    const int l = tid & 63;
    const int rk = l >> 3, c = l & 7;
    const float* base = qkv + (size_t)b * NN * (3*DH);
    const int ldr = tid >> 3, ldc = (tid & 7) * 4;

    float pool0 = 0.f, pool1 = 0.f, pool2 = 0.f, pool3 = 0.f;

    for (int rp = 0; rp < 5; ++rp) {
        const int row = w + 8 * (rp * 8 + rk);
        const bool vrow = (row < NN);
        float4 q4 = make_float4(0.f, 0.f, 0.f, 0.f);
        if (vrow) {
            q4 = *(const float4*)&base[(size_t)row * 768 + hh * HDIM + 4 * c];
            const float sc = 0.17677669529663687f;  // 1/sqrt(32)
            q4.x *= sc; q4.y *= sc; q4.z *= sc; q4.w *= sc;
        }
        float m_run = -1e30f, l_run = 0.f;
        float cx0 = 0.f, cx1 = 0.f, cx2 = 0.f, cx3 = 0.f;
        for (int t = 0; t < 5; ++t) {
            __syncthreads();
            {
                const int jr = t * 64 + ldr;
                float4 kv = make_float4(0.f,0.f,0.f,0.f), vv = make_float4(0.f,0.f,0.f,0.f);
                if (jr < NN) {
                    kv = *(const float4*)&base[(size_t)jr * 768 + 256 + hh * HDIM + ldc];
                    vv = *(const float4*)&base[(size_t)jr * 768 + 512 + hh * HDIM + ldc];
                }
                *(float4*)&kt_s[ldr][ldc] = kv;
                *(float4*)&vt_s[ldr][ldc] = vv;
            }
            __syncthreads();
            float sreg[8];
            #pragma unroll
            for (int j = 0; j < 64; ++j) {
                float4 k4 = *(const float4*)&kt_s[j][4*c];
                float s = q4.x*k4.x + q4.y*k4.y + q4.z*k4.z + q4.w*k4.w;
                s += __shfl_xor(s, 1);
                s += __shfl_xor(s, 2);
                s += __shfl_xor(s, 4);
                if ((j & 7) == c) sreg[j >> 3] = s;   // lane holds j = 8i + c
            }
            if (t == 4) {   // mask j >= N (only final tile)
                #pragma unroll
                for (int i = 0; i < 8; ++i)
                    if (256 + 8*i + c >= NN) sreg[i] = -1e30f;
            }
            float tmax = sreg[0];
            #pragma unroll
            for (int i = 1; i < 8; ++i) tmax = fmaxf(tmax, sreg[i]);
            tmax = fmaxf(tmax, __shfl_xor(tmax, 1));
            tmax = fmaxf(tmax, __shfl_xor(tmax, 2));
            tmax = fmaxf(tmax, __shfl_xor(tmax, 4));
            const float m_new = fmaxf(m_run, tmax);
            const float scale = __expf(m_run - m_new);
            l_run *= scale;
            cx0 *= scale; cx1 *= scale; cx2 *= scale; cx3 *= scale;
            m_run = m_new;
            float p[8];
            #pragma unroll
            for (int i = 0; i < 8; ++i) { p[i] = __expf(sreg[i] - m_new); l_run += p[i]; }
            #pragma unroll
            for (int j = 0; j < 64; ++j) {
                float pj = __shfl(p[j >> 3], (l & 56) | (j & 7));
                float4 v4 = *(const float4*)&vt_s[j][4*c];
                cx0 += pj * v4.x; cx1 += pj * v4.y; cx2 += pj * v4.z; cx3 += pj * v4.w;
            }
        }
        float lt = l_run;
        lt += __shfl_xor(lt, 1);
        lt += __shfl_xor(lt, 2);
        lt += __shfl_xor(lt, 4);
        if (vrow) {
            const float inv = 1.0f / lt;
            pool0 += cx0 * inv; pool1 += cx1 * inv; pool2 += cx2 * inv; pool3 += cx3 * inv;
        }
    }
    pool0 += __shfl_xor(pool0, 8); pool0 += __shfl_xor(pool0, 16); pool0 += __shfl_xor(pool0, 32);
    pool1 += __shfl_xor(pool1, 8); pool1 += __shfl_xor(pool1, 16); pool1 += __shfl_xor(pool1, 32);
    pool2 += __shfl_xor(pool2, 8); pool2 += __shfl_xor(pool2, 16); pool2 += __shfl_xor(pool2, 32);
    pool3 += __shfl_xor(pool3, 8); pool3 += __shfl_xor(pool3, 16); pool3 += __shfl_xor(pool3, 32);
    if (rk == 0) {
        pool_lds[w][4*c+0] = pool0; pool_lds[w][4*c+1] = pool1;
        pool_lds[w][4*c+2] = pool2; pool_lds[w][4*c+3] = pool3;
    }
    __syncthreads();
    if (tid < 32) {
        float s = 0.f;
        #pragma unroll
        for (int ww = 0; ww < 8; ++ww) s += pool_lds[ww][tid];
        pooled[(size_t)b * DH + hh * HDIM + tid] = s * (1.0f / 300.0f);
    }
}

// ------- out = ((pooled @ out_proj^T + bo) @ mlp^T + bm) -------
__global__ __launch_bounds__(256) void k5_head(
    const float* __restrict__ pooled, const float* __restrict__ wo, const float* __restrict__ bo,
    const float* __restrict__ wm, const float* __restrict__ bm, float* __restrict__ out)
{
    __shared__ float pc[DH];
    __shared__ float t1[DH];
    const int b = blockIdx.x, tid = threadIdx.x;
    pc[tid] = pooled[(size_t)b * DH + tid];
    __syncthreads();
    float acc = bo[tid];
    for (int d = 0; d < DH; ++d) acc += pc[d] * wo[(size_t)tid * DH + d];
    t1[tid] = acc;
    __syncthreads();
    float acc2 = bm[tid];
    for (int e2 = 0; e2 < DH; ++e2) acc2 += t1[e2] * wm[(size_t)tid * DH + e2];
    out[(size_t)b * DH + tid] = acc2;
}

extern "C" void kernel_launch(void* const* d_in, const int* in_sizes, int n_in,
                              void* d_out, int out_size, void* d_ws, size_t ws_size,
                              hipStream_t stream) {
    (void)in_sizes; (void)n_in; (void)out_size; (void)ws_size;
    const float* x     = (const float*)d_in[0];
    const int*   src   = (const int*)d_in[1];
    const int*   dst   = (const int*)d_in[2];
    const int*   etype = (const int*)d_in[3];
    const float* wrel  = (const float*)d_in[4];
    const float* wloop = (const float*)d_in[5];
    const float* brel  = (const float*)d_in[6];
    const float* wq    = (const float*)d_in[7];
    const float* bq    = (const float*)d_in[8];
    const float* wo    = (const float*)d_in[9];
    const float* bo    = (const float*)d_in[10];
    const float* wm    = (const float*)d_in[11];
    const float* bm    = (const float*)d_in[12];
    float* out = (float*)d_out;

    float* ws     = (float*)d_ws;
    float* h      = ws;                                   // 38400*256
    float* qkvb   = ws + (size_t)MTOT * DH;               // 38400*768
    float* pooled = qkvb + (size_t)MTOT * (3*DH);         // 128*256
    int*   ibase  = (int*)(pooled + (size_t)BB * DH);
    int*   cnt    = ibase;
    int*   cur    = ibase + 32;
    int*   off    = ibase + 64;
    int*   list   = ibase + 128;                          // 38400 ints

    k0_zero<<<1, 64, 0, stream>>>(cnt, cur);
    k0_count<<<(NEDGE + 255) / 256, 256, 0, stream>>>(etype, cnt);
    k0_scan<<<1, 64, 0, stream>>>(cnt, off);
    k0_fill<<<(NEDGE + 255) / 256, 256, 0, stream>>>(etype, off, cur, list);

    k1_selfloop<<<dim3(MTOT / 64, DH / 64), 256, 0, stream>>>(x, wloop, brel, h);
    k2_relmsg<<<dim3(NEDGE / 64, NREL), 256, 0, stream>>>(x, wrel, src, dst, cnt, off, list, h);
    k3_qkv<<<dim3(MTOT / 64, (3*DH) / 64), 256, 0, stream>>>(h, wq, bq, qkvb);
    k4_attn<<<BB * NHEADS, 512, 0, stream>>>(qkvb, pooled);
    k5_head<<<BB, 256, 0, stream>>>(pooled, wo, bo, wm, bm, out);
}

// Round 2
// 1000.191 us; speedup vs baseline: 1.6390x; 1.6390x over previous
//
#include <hip/hip_runtime.h>
#include <cstdint>
#include <cstddef>

#define BB 128
#define NN 300
#define EE 300
#define DIN 768
#define DH 256
#define NREL 26
#define NHEADS 8
#define HDIM 32
#define MTOT (BB*NN)    // 38400
#define NEDGE (BB*EE)   // 38400

typedef __attribute__((ext_vector_type(8))) short bf16x8;
typedef __attribute__((ext_vector_type(4))) float f32x4;

__device__ __forceinline__ unsigned int packbf2(float a, float b) {
    unsigned int ua = __float_as_uint(a);
    unsigned int ub = __float_as_uint(b);
    ua = (ua + 0x7FFFu + ((ua >> 16) & 1u)) >> 16;
    ub = (ub + 0x7FFFu + ((ub >> 16) & 1u)) & 0xFFFF0000u;
    return ua | ub;
}

// ---------------- edge bucketing by relation ----------------
__global__ void k0_zero(int* __restrict__ cnt, int* __restrict__ cur) {
    int i = threadIdx.x;
    if (i < NREL) { cnt[i] = 0; cur[i] = 0; }
}

__global__ void k0_count(const int* __restrict__ etype, int* __restrict__ cnt) {
    int i = blockIdx.x * 256 + threadIdx.x;
    if (i < NEDGE) atomicAdd(&cnt[etype[i]], 1);
}

__global__ void k0_scan(const int* __restrict__ cnt, int* __restrict__ off) {
    if (threadIdx.x == 0) {
        int acc = 0;
        for (int r = 0; r < NREL; ++r) { off[r] = acc; acc += cnt[r]; }
        off[NREL] = acc;
    }
}

__global__ void k0_fill(const int* __restrict__ etype, const int* __restrict__ off,
                        int* __restrict__ cur, int* __restrict__ list) {
    int i = blockIdx.x * 256 + threadIdx.x;
    if (i < NEDGE) {
        int r = etype[i];
        int p = atomicAdd(&cur[r], 1);
        list[off[r] + p] = i;
    }
}

// ---------------- h = x @ W_loop + b_rel  (M=38400,K=768,N=256) ----------------
__global__ __launch_bounds__(256) void k1_selfloop(
    const float* __restrict__ x, const float* __restrict__ wl,
    const float* __restrict__ brel, float* __restrict__ h)
{
    __shared__ float As[64][17];
    __shared__ float Bs[16][64];
    const int m0 = blockIdx.x * 64, n0 = blockIdx.y * 64;
    const int tid = threadIdx.x;
    const int ty = tid >> 4, tx = tid & 15;
    const int lr = tid >> 2, lk = (tid & 3) * 4;   // A stage
    float acc[4][4] = {};
    for (int kt = 0; kt < DIN; kt += 16) {
        float4 av = *(const float4*)&x[(size_t)(m0 + lr) * DIN + kt + lk];
        As[lr][lk+0] = av.x; As[lr][lk+1] = av.y; As[lr][lk+2] = av.z; As[lr][lk+3] = av.w;
        *(float4*)&Bs[ty][tx*4] = *(const float4*)&wl[(size_t)(kt + ty) * DH + n0 + tx*4];
        __syncthreads();
        #pragma unroll
        for (int k = 0; k < 16; ++k) {
            float4 b4 = *(const float4*)&Bs[k][tx*4];
            #pragma unroll
            for (int i = 0; i < 4; ++i) {
                float a = As[ty*4+i][k];
                acc[i][0] += a * b4.x; acc[i][1] += a * b4.y;
                acc[i][2] += a * b4.z; acc[i][3] += a * b4.w;
            }
        }
        __syncthreads();
    }
    float4 bias = *(const float4*)&brel[n0 + tx*4];
    #pragma unroll
    for (int i = 0; i < 4; ++i) {
        float4 o;
        o.x = acc[i][0] + bias.x; o.y = acc[i][1] + bias.y;
        o.z = acc[i][2] + bias.z; o.w = acc[i][3] + bias.w;
        *(float4*)&h[(size_t)(m0 + ty*4 + i) * DH + n0 + tx*4] = o;
    }
}

// ------- per-relation msg GEMM + scatter-add: h[dst] += x[src] @ W_rel[r] -------
__global__ __launch_bounds__(256) void k2_relmsg(
    const float* __restrict__ x, const float* __restrict__ wrel,
    const int* __restrict__ src, const int* __restrict__ dst,
    const int* __restrict__ cnt, const int* __restrict__ off,
    const int* __restrict__ list, float* __restrict__ h)
{
    __shared__ float As[64][17];
    __shared__ float Bs[16][256];
    __shared__ int arow[64];
    __shared__ int drow[64];
    const int r = blockIdx.y;
    const int c_total = cnt[r];
    const int t0 = blockIdx.x * 64;
    if (t0 >= c_total) return;
    const int tid = threadIdx.x;
    if (tid < 64) {
        int e = t0 + tid;
        if (e < c_total) {
            int eid = list[off[r] + e];
            int b = eid / EE;
            arow[tid] = b * NN + src[eid];
            drow[tid] = b * NN + dst[eid];
        } else { arow[tid] = -1; drow[tid] = -1; }
    }
    __syncthreads();
    const float* wr = wrel + (size_t)r * DIN * DH;
    const int g = tid >> 4, cc = tid & 15;        // compute: rows 4g..4g+3, cols cc+16j
    const int lr = tid >> 2, lk = (tid & 3) * 4;  // A stage
    const int bk = tid >> 4, bc = (tid & 15) * 16; // B stage
    const int ar = arow[lr];
    float acc[4][16] = {};
    for (int kt = 0; kt < DIN; kt += 16) {
        float4 av = make_float4(0.f, 0.f, 0.f, 0.f);
        if (ar >= 0) av = *(const float4*)&x[(size_t)ar * DIN + kt + lk];
        As[lr][lk+0] = av.x; As[lr][lk+1] = av.y; As[lr][lk+2] = av.z; As[lr][lk+3] = av.w;
        #pragma unroll
        for (int q = 0; q < 4; ++q)
            *(float4*)&Bs[bk][bc + 4*q] = *(const float4*)&wr[(size_t)(kt + bk) * DH + bc + 4*q];
        __syncthreads();
        #pragma unroll
        for (int k = 0; k < 16; ++k) {
            float a_[4];
            #pragma unroll
            for (int i = 0; i < 4; ++i) a_[i] = As[4*g+i][k];
            #pragma unroll
            for (int j = 0; j < 16; ++j) {
                float bv = Bs[k][cc + 16*j];
                #pragma unroll
                for (int i = 0; i < 4; ++i) acc[i][j] += a_[i] * bv;
            }
        }
        __syncthreads();
    }
    #pragma unroll
    for (int i = 0; i < 4; ++i) {
        int dr = drow[4*g+i];
        if (dr >= 0) {
            #pragma unroll
            for (int j = 0; j < 16; ++j)
                atomicAdd(&h[(size_t)dr * DH + cc + 16*j], acc[i][j]);
        }
    }
}

// ---------------- qkv = h @ in_proj_w^T + in_proj_b (M=38400,K=256,N=768) ----------------
__global__ __launch_bounds__(256) void k3_qkv(
    const float* __restrict__ h, const float* __restrict__ wq,
    const float* __restrict__ bq, float* __restrict__ qkv)
{
    __shared__ float As[64][17];
    __shared__ float Bs[16][68];
    const int m0 = blockIdx.x * 64, j0 = blockIdx.y * 64;
    const int tid = threadIdx.x;
    const int ty = tid >> 4, tx = tid & 15;
    const int lr = tid >> 2, lk = (tid & 3) * 4;
    float acc[4][4] = {};
    for (int kt = 0; kt < DH; kt += 16) {
        float4 av = *(const float4*)&h[(size_t)(m0 + lr) * DH + kt + lk];
        As[lr][lk+0] = av.x; As[lr][lk+1] = av.y; As[lr][lk+2] = av.z; As[lr][lk+3] = av.w;
        // B transpose-stage: Bs[k][j] = wq[(j0+j)*DH + kt+k]
        float4 wv = *(const float4*)&wq[(size_t)(j0 + lr) * DH + kt + lk];
        Bs[lk+0][lr] = wv.x; Bs[lk+1][lr] = wv.y; Bs[lk+2][lr] = wv.z; Bs[lk+3][lr] = wv.w;
        __syncthreads();
        #pragma unroll
        for (int k = 0; k < 16; ++k) {
            float4 b4 = *(const float4*)&Bs[k][tx*4];
            #pragma unroll
            for (int i = 0; i < 4; ++i) {
                float a = As[ty*4+i][k];
                acc[i][0] += a * b4.x; acc[i][1] += a * b4.y;
                acc[i][2] += a * b4.z; acc[i][3] += a * b4.w;
            }
        }
        __syncthreads();
    }
    float4 bias = *(const float4*)&bq[j0 + tx*4];
    #pragma unroll
    for (int i = 0; i < 4; ++i) {
        float4 o;
        o.x = acc[i][0] + bias.x; o.y = acc[i][1] + bias.y;
        o.z = acc[i][2] + bias.z; o.w = acc[i][3] + bias.w;
        *(float4*)&qkv[(size_t)(m0 + ty*4 + i) * (3*DH) + j0 + tx*4] = o;
    }
}

// ------- MFMA flash attention per (b,head) + fused mean-pool -------
// S^T = mfma(A=K, B=Q): lane holds col q=l&15, rows j=16*jt+4*(l>>4)+i.
// Softmax over j: local regs + shfl_xor(16,32).
// PV: ctx^T = mfma(A=V^T, B=P^T). P^T C-layout (j=4g+i) -> B-frag (j=8g+m)
// via 8 shuffles per 32-j chunk.
__global__ __launch_bounds__(256) void k4_attn(
    const float* __restrict__ qkv, float* __restrict__ pooled)
{
    __shared__ uint4 kfrag[19*64];     // K A-frags: lane l: K[16jt+(l&15)][8*(l>>4)..+7]
    __shared__ uint4 vtfrag[20*64];    // V^T A-frags: [dt][c]: lane l: V[32c+8*(l>>4)+m][16dt+(l&15)]
    __shared__ float pool_lds[4][32];
    const int bh = blockIdx.x;
    const int b = bh >> 3, hh = bh & 7;
    const int tid = threadIdx.x;
    const float* base = qkv + (size_t)b * NN * 768;

    // ---- stage K fragments (bf16, fragment order, linear) ----
    for (int s = tid; s < 19*64; s += 256) {
        int jt = s >> 6, l = s & 63;
        int j = jt * 16 + (l & 15);
        int d0 = (l >> 4) * 8;
        uint4 w = make_uint4(0u, 0u, 0u, 0u);
        if (j < NN) {
            const float* p = base + (size_t)j * 768 + 256 + hh * HDIM + d0;
            float4 f0 = *(const float4*)p;
            float4 f1 = *(const float4*)(p + 4);
            w.x = packbf2(f0.x, f0.y); w.y = packbf2(f0.z, f0.w);
            w.z = packbf2(f1.x, f1.y); w.w = packbf2(f1.z, f1.w);
        }
        kfrag[s] = w;
    }
    // ---- stage V^T fragments ----
    for (int s = tid; s < 20*64; s += 256) {
        int dt = s / 640;
        int rem = s - dt * 640;
        int c = rem >> 6, l = rem & 63;
        int d = dt * 16 + (l & 15);
        int j0 = c * 32 + (l >> 4) * 8;
        float f[8];
        #pragma unroll
        for (int jj = 0; jj < 8; ++jj) {
            int j = j0 + jj;
            f[jj] = (j < NN) ? base[(size_t)j * 768 + 512 + hh * HDIM + d] : 0.f;
        }
        uint4 w;
        w.x = packbf2(f[0], f[1]); w.y = packbf2(f[2], f[3]);
        w.z = packbf2(f[4], f[5]); w.w = packbf2(f[6], f[7]);
        vtfrag[s] = w;
    }
    __syncthreads();

    const int w = tid >> 6;
    const int l = tid & 63;
    const int g = l >> 4, q = l & 15;
    const int srcA = (((2*g) & 3) << 4) | q;
    const int srcB = (((2*g + 1) & 3) << 4) | q;
    const bool hi = (g >= 2);

    float pool[8] = {0.f,0.f,0.f,0.f,0.f,0.f,0.f,0.f};  // [dt*4+i], d = 16*dt + 4*g + i

    for (int qt = w; qt < 19; qt += 4) {
        // Q B-frag straight from global (32B contiguous per lane)
        int qrow = qt * 16 + q;
        int d0 = g * 8;
        uint4 qw = make_uint4(0u, 0u, 0u, 0u);
        if (qrow < NN) {
            const float* p = base + (size_t)qrow * 768 + hh * HDIM + d0;
            float4 f0 = *(const float4*)p;
            float4 f1 = *(const float4*)(p + 4);
            const float sc = 0.17677669529663687f;  // 1/sqrt(32)
            qw.x = packbf2(f0.x * sc, f0.y * sc); qw.y = packbf2(f0.z * sc, f0.w * sc);
            qw.z = packbf2(f1.x * sc, f1.y * sc); qw.w = packbf2(f1.z * sc, f1.w * sc);
        }
        union { uint4 u; bf16x8 v; } uq; uq.u = qw;

        // ---- S^T: 19 MFMAs ----
        f32x4 s_[19];
        #pragma unroll
        for (int jt = 0; jt < 19; ++jt) {
            union { uint4 u; bf16x8 v; } uk; uk.u = kfrag[jt * 64 + l];
            f32x4 z = {0.f, 0.f, 0.f, 0.f};
            s_[jt] = __builtin_amdgcn_mfma_f32_16x16x32_bf16(uk.v, uq.v, z, 0, 0, 0);
        }
        // mask j = 300..303 (tile 18, rows 12..15 => group 3)
        if (g == 3) { s_[18][0] = -1e30f; s_[18][1] = -1e30f; s_[18][2] = -1e30f; s_[18][3] = -1e30f; }

        // ---- softmax over j (column q is lane-local + 2 shuffles) ----
        float m = -1e30f;
        #pragma unroll
        for (int jt = 0; jt < 19; ++jt)
            m = fmaxf(m, fmaxf(fmaxf(s_[jt][0], s_[jt][1]), fmaxf(s_[jt][2], s_[jt][3])));
        m = fmaxf(m, __shfl_xor(m, 16));
        m = fmaxf(m, __shfl_xor(m, 32));

        float lsum = 0.f;
        unsigned int pk[19][2];
        #pragma unroll
        for (int jt = 0; jt < 19; ++jt) {
            float p0 = __expf(s_[jt][0] - m);
            float p1 = __expf(s_[jt][1] - m);
            float p2 = __expf(s_[jt][2] - m);
            float p3 = __expf(s_[jt][3] - m);
            lsum += (p0 + p1) + (p2 + p3);
            pk[jt][0] = packbf2(p0, p1);
            pk[jt][1] = packbf2(p2, p3);
        }
        lsum += __shfl_xor(lsum, 16);
        lsum += __shfl_xor(lsum, 32);

        // ---- PV: 10 chunks x (8 shuffles + 2 MFMAs) ----
        f32x4 ctx0 = {0.f,0.f,0.f,0.f}, ctx1 = {0.f,0.f,0.f,0.f};
        #pragma unroll
        for (int c = 0; c < 10; ++c) {
            unsigned int t0w0 = pk[2*c][0], t0w1 = pk[2*c][1];
            unsigned int t1w0 = (2*c + 1 < 19) ? pk[2*c+1][0] : 0u;
            unsigned int t1w1 = (2*c + 1 < 19) ? pk[2*c+1][1] : 0u;
            int xA0 = __shfl((int)t0w0, srcA), yA0 = __shfl((int)t1w0, srcA);
            int xA1 = __shfl((int)t0w1, srcA), yA1 = __shfl((int)t1w1, srcA);
            int xB0 = __shfl((int)t0w0, srcB), yB0 = __shfl((int)t1w0, srcB);
            int xB1 = __shfl((int)t0w1, srcB), yB1 = __shfl((int)t1w1, srcB);
            uint4 pu;
            pu.x = (unsigned)(hi ? yA0 : xA0);
            pu.y = (unsigned)(hi ? yA1 : xA1);
            pu.z = (unsigned)(hi ? yB0 : xB0);
            pu.w = (unsigned)(hi ? yB1 : xB1);
            union { uint4 u; bf16x8 v; } up;  up.u = pu;
            union { uint4 u; bf16x8 v; } uv0; uv0.u = vtfrag[c * 64 + l];
            union { uint4 u; bf16x8 v; } uv1; uv1.u = vtfrag[(10 + c) * 64 + l];
            ctx0 = __builtin_amdgcn_mfma_f32_16x16x32_bf16(uv0.v, up.v, ctx0, 0, 0, 0);
            ctx1 = __builtin_amdgcn_mfma_f32_16x16x32_bf16(uv1.v, up.v, ctx1, 0, 0, 0);
        }
        if (qrow < NN) {
            float inv = 1.0f / lsum;
            pool[0] += ctx0[0] * inv; pool[1] += ctx0[1] * inv;
            pool[2] += ctx0[2] * inv; pool[3] += ctx0[3] * inv;
            pool[4] += ctx1[0] * inv; pool[5] += ctx1[1] * inv;
            pool[6] += ctx1[2] * inv; pool[7] += ctx1[3] * inv;
        }
    }

    // reduce pool over q lanes (bits 0..3), then across waves via LDS
    #pragma unroll
    for (int i = 0; i < 8; ++i) {
        float v = pool[i];
        v += __shfl_xor(v, 1); v += __shfl_xor(v, 2);
        v += __shfl_xor(v, 4); v += __shfl_xor(v, 8);
        pool[i] = v;
    }
    if (q == 0) {
        #pragma unroll
        for (int dt = 0; dt < 2; ++dt)
            #pragma unroll
            for (int i = 0; i < 4; ++i)
                pool_lds[w][dt * 16 + 4 * g + i] = pool[dt * 4 + i];
    }
    __syncthreads();
    if (tid < 32) {
        float s = pool_lds[0][tid] + pool_lds[1][tid] + pool_lds[2][tid] + pool_lds[3][tid];
        pooled[(size_t)b * DH + hh * HDIM + tid] = s * (1.0f / 300.0f);
    }
}

// ------- out = ((pooled @ out_proj^T + bo) @ mlp^T + bm) -------
__global__ __launch_bounds__(256) void k5_head(
    const float* __restrict__ pooled, const float* __restrict__ wo, const float* __restrict__ bo,
    const float* __restrict__ wm, const float* __restrict__ bm, float* __restrict__ out)
{
    __shared__ float pc[DH];
    __shared__ float t1[DH];
    const int b = blockIdx.x, tid = threadIdx.x;
    pc[tid] = pooled[(size_t)b * DH + tid];
    __syncthreads();
    float acc = bo[tid];
    for (int d = 0; d < DH; ++d) acc += pc[d] * wo[(size_t)tid * DH + d];
    t1[tid] = acc;
    __syncthreads();
    float acc2 = bm[tid];
    for (int e2 = 0; e2 < DH; ++e2) acc2 += t1[e2] * wm[(size_t)tid * DH + e2];
    out[(size_t)b * DH + tid] = acc2;
}

extern "C" void kernel_launch(void* const* d_in, const int* in_sizes, int n_in,
                              void* d_out, int out_size, void* d_ws, size_t ws_size,
                              hipStream_t stream) {
    (void)in_sizes; (void)n_in; (void)out_size; (void)ws_size;
    const float* x     = (const float*)d_in[0];
    const int*   src   = (const int*)d_in[1];
    const int*   dst   = (const int*)d_in[2];
    const int*   etype = (const int*)d_in[3];
    const float* wrel  = (const float*)d_in[4];
    const float* wloop = (const float*)d_in[5];
    const float* brel  = (const float*)d_in[6];
    const float* wq    = (const float*)d_in[7];
    const float* bq    = (const float*)d_in[8];
    const float* wo    = (const float*)d_in[9];
    const float* bo    = (const float*)d_in[10];
    const float* wm    = (const float*)d_in[11];
    const float* bm    = (const float*)d_in[12];
    float* out = (float*)d_out;

    float* ws     = (float*)d_ws;
    float* h      = ws;                                   // 38400*256
    float* qkvb   = ws + (size_t)MTOT * DH;               // 38400*768
    float* pooled = qkvb + (size_t)MTOT * (3*DH);         // 128*256
    int*   ibase  = (int*)(pooled + (size_t)BB * DH);
    int*   cnt    = ibase;
    int*   cur    = ibase + 32;
    int*   off    = ibase + 64;
    int*   list   = ibase + 128;                          // 38400 ints

    k0_zero<<<1, 64, 0, stream>>>(cnt, cur);
    k0_count<<<(NEDGE + 255) / 256, 256, 0, stream>>>(etype, cnt);
    k0_scan<<<1, 64, 0, stream>>>(cnt, off);
    k0_fill<<<(NEDGE + 255) / 256, 256, 0, stream>>>(etype, off, cur, list);

    k1_selfloop<<<dim3(MTOT / 64, DH / 64), 256, 0, stream>>>(x, wloop, brel, h);
    k2_relmsg<<<dim3(NEDGE / 64, NREL), 256, 0, stream>>>(x, wrel, src, dst, cnt, off, list, h);
    k3_qkv<<<dim3(MTOT / 64, (3*DH) / 64), 256, 0, stream>>>(h, wq, bq, qkvb);
    k4_attn<<<BB * NHEADS, 256, 0, stream>>>(qkvb, pooled);
    k5_head<<<BB, 256, 0, stream>>>(pooled, wo, bo, wm, bm, out);
}

// Round 3
// 428.859 us; speedup vs baseline: 3.8225x; 2.3322x over previous
//
#include <hip/hip_runtime.h>
#include <cstdint>
#include <cstddef>

#define BB 128
#define NN 300
#define EE 300
#define DIN 768
#define DH 256
#define NREL 26
#define NHEADS 8
#define HDIM 32
#define MTOT (BB*NN)    // 38400
#define NEDGE (BB*EE)   // 38400

typedef __attribute__((ext_vector_type(8))) short bf16x8;
typedef __attribute__((ext_vector_type(4))) float f32x4;
typedef unsigned short u16;
union BU { uint4 u; bf16x8 v; };

__device__ __forceinline__ unsigned int packbf2(float a, float b) {
    unsigned int ua = __float_as_uint(a);
    unsigned int ub = __float_as_uint(b);
    ua = (ua + 0x7FFFu + ((ua >> 16) & 1u)) >> 16;
    ub = (ub + 0x7FFFu + ((ub >> 16) & 1u)) & 0xFFFF0000u;
    return ua | ub;
}
__device__ __forceinline__ u16 packbf1(float a) {
    unsigned int ua = __float_as_uint(a);
    return (u16)((ua + 0x7FFFu + ((ua >> 16) & 1u)) >> 16);
}

// ---------------- edge bucketing by relation ----------------
__global__ void k0_zero(int* __restrict__ cnt, int* __restrict__ cur) {
    int i = threadIdx.x;
    if (i < NREL) { cnt[i] = 0; cur[i] = 0; }
}
__global__ void k0_count(const int* __restrict__ etype, int* __restrict__ cnt) {
    int i = blockIdx.x * 256 + threadIdx.x;
    if (i < NEDGE) atomicAdd(&cnt[etype[i]], 1);
}
__global__ void k0_scan(const int* __restrict__ cnt, int* __restrict__ off) {
    if (threadIdx.x == 0) {
        int acc = 0;
        for (int r = 0; r < NREL; ++r) { off[r] = acc; acc += cnt[r]; }
        off[NREL] = acc;
    }
}
__global__ void k0_fill(const int* __restrict__ etype, const int* __restrict__ off,
                        int* __restrict__ cur, int* __restrict__ list) {
    int i = blockIdx.x * 256 + threadIdx.x;
    if (i < NEDGE) {
        int r = etype[i];
        int p = atomicAdd(&cur[r], 1);
        list[off[r] + p] = i;
    }
}

// ---------------- casts ----------------
// 8 floats -> 8 bf16 per thread
__global__ __launch_bounds__(256) void c_cast8(const float4* __restrict__ in,
                                               uint4* __restrict__ out, int n8) {
    int i = blockIdx.x * 256 + threadIdx.x;
    if (i < n8) {
        float4 f0 = in[2*i], f1 = in[2*i+1];
        uint4 o;
        o.x = packbf2(f0.x, f0.y); o.y = packbf2(f0.z, f0.w);
        o.z = packbf2(f1.x, f1.y); o.w = packbf2(f1.z, f1.w);
        out[i] = o;
    }
}

// Pack weights into MFMA B-fragment order.
// B-frag (kf,nt), lane l: 8 bf16 = B[32kf+8*(l>>4)+t][16nt+(l&15)], t=0..7.
// wrel: B=W_rel[r][k][n] (strided gather). wl: B=W_loop[k][n]. wq: B[k=d][n=e]=in_proj_w[e][d] (contiguous).
__global__ __launch_bounds__(256) void c_cast_w(
    const float* __restrict__ wrel, const float* __restrict__ wl, const float* __restrict__ wq,
    uint4* __restrict__ wrb, uint4* __restrict__ wlb, uint4* __restrict__ wqb) {
    int t = blockIdx.x * 256 + threadIdx.x;
    int l = t & 63, fid = t >> 6;
    if (fid < NREL*24*16) {
        int r = fid / 384, rem = fid - r * 384;
        int kf = rem >> 4, nt = rem & 15;
        int k0 = 32*kf + 8*(l >> 4), n = 16*nt + (l & 15);
        const float* p = wrel + ((size_t)r*768 + k0) * 256 + n;
        uint4 o;
        o.x = packbf2(p[0], p[256]); o.y = packbf2(p[512], p[768]);
        o.z = packbf2(p[1024], p[1280]); o.w = packbf2(p[1536], p[1792]);
        wrb[t] = o;
    } else if (fid < NREL*24*16 + 384) {
        int f2 = fid - NREL*24*16;
        int kf = f2 >> 4, nt = f2 & 15;
        int k0 = 32*kf + 8*(l >> 4), n = 16*nt + (l & 15);
        const float* p = wl + (size_t)k0 * 256 + n;
        uint4 o;
        o.x = packbf2(p[0], p[256]); o.y = packbf2(p[512], p[768]);
        o.z = packbf2(p[1024], p[1280]); o.w = packbf2(p[1536], p[1792]);
        wlb[f2*64 + l] = o;
    } else {
        int f2 = fid - NREL*24*16 - 384;   // kf*48 + nt
        int kf = f2 / 48, nt = f2 % 48;
        int e = 16*nt + (l & 15), d0 = 32*kf + 8*(l >> 4);
        const float4* p = (const float4*)(wq + (size_t)e * 256 + d0);
        float4 f0 = p[0], f1 = p[1];
        uint4 o;
        o.x = packbf2(f0.x, f0.y); o.y = packbf2(f0.z, f0.w);
        o.z = packbf2(f1.x, f1.y); o.w = packbf2(f1.z, f1.w);
        wqb[f2*64 + l] = o;
    }
}

// ---------------- MFMA GEMM: h = xb @ wlb + b_rel  (64x128 tile) ----------------
__global__ __launch_bounds__(256) void k1m(
    const uint4* __restrict__ xb, const uint4* __restrict__ wlb,
    const float* __restrict__ brel, float* __restrict__ h) {
    __shared__ uint4 As[512];
    const int tid = threadIdx.x;
    const int m0 = blockIdx.x * 64;
    const int nb = blockIdx.y;           // n-half: cols nb*128..+127, n-tiles nb*8..+7
    const int w = tid >> 6, l = tid & 63;
    const int g = l >> 4, q = l & 15;
    int cA[2];
    #pragma unroll
    for (int p = 0; p < 2; ++p) {
        int s = tid + p * 256;
        int fi = s >> 6, l2 = s & 63;
        int kf = fi >> 2, mt = fi & 3;
        int row = m0 + 16*mt + (l2 & 15);
        cA[p] = row * 96 + 4*kf + (l2 >> 4);
    }
    f32x4 acc[4][2];
    #pragma unroll
    for (int a = 0; a < 4; ++a)
        #pragma unroll
        for (int n = 0; n < 2; ++n) acc[a][n] = (f32x4){0.f,0.f,0.f,0.f};

    for (int step = 0; step < 12; ++step) {
        uint4 a0 = xb[cA[0] + step*8];
        uint4 a1 = xb[cA[1] + step*8];
        BU Bf[2][2];
        #pragma unroll
        for (int kf = 0; kf < 2; ++kf)
            #pragma unroll
            for (int nt = 0; nt < 2; ++nt)
                Bf[kf][nt].u = wlb[((step*2 + kf)*16 + nb*8 + w*2 + nt)*64 + l];
        __syncthreads();
        As[tid] = a0; As[tid + 256] = a1;
        __syncthreads();
        #pragma unroll
        for (int kf = 0; kf < 2; ++kf) {
            BU Af[4];
            #pragma unroll
            for (int mt = 0; mt < 4; ++mt) Af[mt].u = As[(kf*4 + mt)*64 + l];
            #pragma unroll
            for (int mt = 0; mt < 4; ++mt)
                #pragma unroll
                for (int nt = 0; nt < 2; ++nt)
                    acc[mt][nt] = __builtin_amdgcn_mfma_f32_16x16x32_bf16(Af[mt].v, Bf[kf][nt].v, acc[mt][nt], 0, 0, 0);
        }
    }
    #pragma unroll
    for (int nt = 0; nt < 2; ++nt) {
        int col = nb*128 + w*32 + nt*16 + q;
        float bias = brel[col];
        #pragma unroll
        for (int mt = 0; mt < 4; ++mt)
            #pragma unroll
            for (int i = 0; i < 4; ++i)
                h[(size_t)(m0 + 16*mt + 4*g + i)*256 + col] = acc[mt][nt][i] + bias;
    }
}

// ------- MFMA per-relation msg GEMM + scatter-add -------
__global__ __launch_bounds__(256) void k2m(
    const uint4* __restrict__ xb, const uint4* __restrict__ wrb,
    const int* __restrict__ src, const int* __restrict__ dst,
    const int* __restrict__ cnt, const int* __restrict__ off,
    const int* __restrict__ list, float* __restrict__ h) {
    __shared__ uint4 As[512];
    __shared__ int arow_s[64];
    __shared__ int drow_s[64];
    const int r = blockIdx.y;
    const int c_total = cnt[r];
    const int t0 = blockIdx.x * 64;
    if (t0 >= c_total) return;
    const int nb = blockIdx.z;
    const int tid = threadIdx.x;
    if (tid < 64) {
        int e = t0 + tid;
        int ar = 0, dr = -1;
        if (e < c_total) {
            int eid = list[off[r] + e];
            int b = eid / EE;
            ar = b * NN + src[eid];
            dr = b * NN + dst[eid];
        }
        arow_s[tid] = ar; drow_s[tid] = dr;
    }
    __syncthreads();
    const int w = tid >> 6, l = tid & 63;
    const int g = l >> 4, q = l & 15;
    int cA[2];
    #pragma unroll
    for (int p = 0; p < 2; ++p) {
        int s = tid + p * 256;
        int fi = s >> 6, l2 = s & 63;
        int kf = fi >> 2, mt = fi & 3;
        int row = arow_s[16*mt + (l2 & 15)];
        cA[p] = row * 96 + 4*kf + (l2 >> 4);
    }
    const uint4* wb = wrb + (size_t)r * 24*16*64;
    f32x4 acc[4][2];
    #pragma unroll
    for (int a = 0; a < 4; ++a)
        #pragma unroll
        for (int n = 0; n < 2; ++n) acc[a][n] = (f32x4){0.f,0.f,0.f,0.f};

    for (int step = 0; step < 12; ++step) {
        uint4 a0 = xb[cA[0] + step*8];
        uint4 a1 = xb[cA[1] + step*8];
        BU Bf[2][2];
        #pragma unroll
        for (int kf = 0; kf < 2; ++kf)
            #pragma unroll
            for (int nt = 0; nt < 2; ++nt)
                Bf[kf][nt].u = wb[((step*2 + kf)*16 + nb*8 + w*2 + nt)*64 + l];
        __syncthreads();
        As[tid] = a0; As[tid + 256] = a1;
        __syncthreads();
        #pragma unroll
        for (int kf = 0; kf < 2; ++kf) {
            BU Af[4];
            #pragma unroll
            for (int mt = 0; mt < 4; ++mt) Af[mt].u = As[(kf*4 + mt)*64 + l];
            #pragma unroll
            for (int mt = 0; mt < 4; ++mt)
                #pragma unroll
                for (int nt = 0; nt < 2; ++nt)
                    acc[mt][nt] = __builtin_amdgcn_mfma_f32_16x16x32_bf16(Af[mt].v, Bf[kf][nt].v, acc[mt][nt], 0, 0, 0);
        }
    }
    #pragma unroll
    for (int mt = 0; mt < 4; ++mt)
        #pragma unroll
        for (int i = 0; i < 4; ++i) {
            int dr = drow_s[16*mt + 4*g + i];
            if (dr >= 0) {
                #pragma unroll
                for (int nt = 0; nt < 2; ++nt)
                    atomicAdd(&h[(size_t)dr*256 + nb*128 + w*32 + nt*16 + q], acc[mt][nt][i]);
            }
        }
}

// ---------------- MFMA qkv = hb @ wqb^T + bias, bf16 out ----------------
__global__ __launch_bounds__(256) void k3m(
    const uint4* __restrict__ hb, const uint4* __restrict__ wqb,
    const float* __restrict__ bq, u16* __restrict__ qkvb) {
    __shared__ uint4 As[512];
    const int tid = threadIdx.x;
    const int m0 = blockIdx.x * 64;
    const int nb = blockIdx.y;           // 6 n-spans of 128
    const int w = tid >> 6, l = tid & 63;
    const int g = l >> 4, q = l & 15;
    int cA[2];
    #pragma unroll
    for (int p = 0; p < 2; ++p) {
        int s = tid + p * 256;
        int fi = s >> 6, l2 = s & 63;
        int kf = fi >> 2, mt = fi & 3;
        int row = m0 + 16*mt + (l2 & 15);
        cA[p] = row * 32 + 4*kf + (l2 >> 4);
    }
    f32x4 acc[4][2];
    #pragma unroll
    for (int a = 0; a < 4; ++a)
        #pragma unroll
        for (int n = 0; n < 2; ++n) acc[a][n] = (f32x4){0.f,0.f,0.f,0.f};

    for (int step = 0; step < 4; ++step) {
        uint4 a0 = hb[cA[0] + step*8];
        uint4 a1 = hb[cA[1] + step*8];
        BU Bf[2][2];
        #pragma unroll
        for (int kf = 0; kf < 2; ++kf)
            #pragma unroll
            for (int nt = 0; nt < 2; ++nt)
                Bf[kf][nt].u = wqb[((step*2 + kf)*48 + nb*8 + w*2 + nt)*64 + l];
        __syncthreads();
        As[tid] = a0; As[tid + 256] = a1;
        __syncthreads();
        #pragma unroll
        for (int kf = 0; kf < 2; ++kf) {
            BU Af[4];
            #pragma unroll
            for (int mt = 0; mt < 4; ++mt) Af[mt].u = As[(kf*4 + mt)*64 + l];
            #pragma unroll
            for (int mt = 0; mt < 4; ++mt)
                #pragma unroll
                for (int nt = 0; nt < 2; ++nt)
                    acc[mt][nt] = __builtin_amdgcn_mfma_f32_16x16x32_bf16(Af[mt].v, Bf[kf][nt].v, acc[mt][nt], 0, 0, 0);
        }
    }
    #pragma unroll
    for (int nt = 0; nt < 2; ++nt) {
        int e = nb*128 + w*32 + nt*16 + q;
        float bias = bq[e];
        #pragma unroll
        for (int mt = 0; mt < 4; ++mt)
            #pragma unroll
            for (int i = 0; i < 4; ++i)
                qkvb[(size_t)(m0 + 16*mt + 4*g + i)*768 + e] = packbf1(acc[mt][nt][i] + bias);
    }
}

// ------- MFMA flash attention (bf16 qkv) + fused mean-pool -------
__global__ __launch_bounds__(256) void k4_attn(
    const u16* __restrict__ qkv, float* __restrict__ pooled) {
    __shared__ uint4 kfrag[19*64];
    __shared__ uint4 vtfrag[20*64];
    __shared__ float pool_lds[4][32];
    const int bh = blockIdx.x;
    const int b = bh >> 3, hh = bh & 7;
    const int tid = threadIdx.x;
    const u16* base = qkv + (size_t)b * NN * 768;
    const uint4* base4 = (const uint4*)base;

    for (int s = tid; s < 19*64; s += 256) {
        int jt = s >> 6, l = s & 63;
        int j = jt * 16 + (l & 15);
        uint4 wv = make_uint4(0u, 0u, 0u, 0u);
        if (j < NN) wv = base4[j*96 + 32 + hh*4 + (l >> 4)];
        kfrag[s] = wv;
    }
    for (int s = tid; s < 20*64; s += 256) {
        int dt = s / 640;
        int rem = s - dt * 640;
        int c = rem >> 6, l = rem & 63;
        int d = dt * 16 + (l & 15);
        int j0 = c * 32 + (l >> 4) * 8;
        u16 us[8];
        #pragma unroll
        for (int jj = 0; jj < 8; ++jj) {
            int j = j0 + jj;
            us[jj] = (j < NN) ? base[(size_t)j*768 + 512 + hh*32 + d] : (u16)0;
        }
        uint4 wv;
        wv.x = us[0] | ((unsigned)us[1] << 16);
        wv.y = us[2] | ((unsigned)us[3] << 16);
        wv.z = us[4] | ((unsigned)us[5] << 16);
        wv.w = us[6] | ((unsigned)us[7] << 16);
        vtfrag[s] = wv;
    }
    __syncthreads();

    const int w = tid >> 6;
    const int l = tid & 63;
    const int g = l >> 4, q = l & 15;
    const int srcA = (((2*g) & 3) << 4) | q;
    const int srcB = (((2*g + 1) & 3) << 4) | q;
    const bool hi = (g >= 2);

    float pool[8] = {0.f,0.f,0.f,0.f,0.f,0.f,0.f,0.f};

    for (int qt = w; qt < 19; qt += 4) {
        int qrow = qt * 16 + q;
        uint4 qw = make_uint4(0u, 0u, 0u, 0u);
        if (qrow < NN) qw = base4[qrow*96 + hh*4 + g];
        BU uq; uq.u = qw;

        f32x4 s_[19];
        #pragma unroll
        for (int jt = 0; jt < 19; ++jt) {
            BU uk; uk.u = kfrag[jt * 64 + l];
            f32x4 z = {0.f, 0.f, 0.f, 0.f};
            s_[jt] = __builtin_amdgcn_mfma_f32_16x16x32_bf16(uk.v, uq.v, z, 0, 0, 0);
        }
        const float sc = 0.17677669529663687f;  // 1/sqrt(32)
        #pragma unroll
        for (int jt = 0; jt < 19; ++jt) {
            s_[jt][0] *= sc; s_[jt][1] *= sc; s_[jt][2] *= sc; s_[jt][3] *= sc;
        }
        if (g == 3) { s_[18][0] = -1e30f; s_[18][1] = -1e30f; s_[18][2] = -1e30f; s_[18][3] = -1e30f; }

        float m = -1e30f;
        #pragma unroll
        for (int jt = 0; jt < 19; ++jt)
            m = fmaxf(m, fmaxf(fmaxf(s_[jt][0], s_[jt][1]), fmaxf(s_[jt][2], s_[jt][3])));
        m = fmaxf(m, __shfl_xor(m, 16));
        m = fmaxf(m, __shfl_xor(m, 32));

        float lsum = 0.f;
        unsigned int pk[19][2];
        #pragma unroll
        for (int jt = 0; jt < 19; ++jt) {
            float p0 = __expf(s_[jt][0] - m);
            float p1 = __expf(s_[jt][1] - m);
            float p2 = __expf(s_[jt][2] - m);
            float p3 = __expf(s_[jt][3] - m);
            lsum += (p0 + p1) + (p2 + p3);
            pk[jt][0] = packbf2(p0, p1);
            pk[jt][1] = packbf2(p2, p3);
        }
        lsum += __shfl_xor(lsum, 16);
        lsum += __shfl_xor(lsum, 32);

        f32x4 ctx0 = {0.f,0.f,0.f,0.f}, ctx1 = {0.f,0.f,0.f,0.f};
        #pragma unroll
        for (int c = 0; c < 10; ++c) {
            unsigned int t0w0 = pk[2*c][0], t0w1 = pk[2*c][1];
            unsigned int t1w0 = (2*c + 1 < 19) ? pk[2*c+1][0] : 0u;
            unsigned int t1w1 = (2*c + 1 < 19) ? pk[2*c+1][1] : 0u;
            int xA0 = __shfl((int)t0w0, srcA), yA0 = __shfl((int)t1w0, srcA);
            int xA1 = __shfl((int)t0w1, srcA), yA1 = __shfl((int)t1w1, srcA);
            int xB0 = __shfl((int)t0w0, srcB), yB0 = __shfl((int)t1w0, srcB);
            int xB1 = __shfl((int)t0w1, srcB), yB1 = __shfl((int)t1w1, srcB);
            uint4 pu;
            pu.x = (unsigned)(hi ? yA0 : xA0);
            pu.y = (unsigned)(hi ? yA1 : xA1);
            pu.z = (unsigned)(hi ? yB0 : xB0);
            pu.w = (unsigned)(hi ? yB1 : xB1);
            BU up;  up.u = pu;
            BU uv0; uv0.u = vtfrag[c * 64 + l];
            BU uv1; uv1.u = vtfrag[(10 + c) * 64 + l];
            ctx0 = __builtin_amdgcn_mfma_f32_16x16x32_bf16(uv0.v, up.v, ctx0, 0, 0, 0);
            ctx1 = __builtin_amdgcn_mfma_f32_16x16x32_bf16(uv1.v, up.v, ctx1, 0, 0, 0);
        }
        if (qrow < NN) {
            float inv = 1.0f / lsum;
            pool[0] += ctx0[0] * inv; pool[1] += ctx0[1] * inv;
            pool[2] += ctx0[2] * inv; pool[3] += ctx0[3] * inv;
            pool[4] += ctx1[0] * inv; pool[5] += ctx1[1] * inv;
            pool[6] += ctx1[2] * inv; pool[7] += ctx1[3] * inv;
        }
    }

    #pragma unroll
    for (int i = 0; i < 8; ++i) {
        float v = pool[i];
        v += __shfl_xor(v, 1); v += __shfl_xor(v, 2);
        v += __shfl_xor(v, 4); v += __shfl_xor(v, 8);
        pool[i] = v;
    }
    if (q == 0) {
        #pragma unroll
        for (int dt = 0; dt < 2; ++dt)
            #pragma unroll
            for (int i = 0; i < 4; ++i)
                pool_lds[w][dt * 16 + 4 * g + i] = pool[dt * 4 + i];
    }
    __syncthreads();
    if (tid < 32) {
        float s = pool_lds[0][tid] + pool_lds[1][tid] + pool_lds[2][tid] + pool_lds[3][tid];
        pooled[(size_t)b * DH + hh * HDIM + tid] = s * (1.0f / 300.0f);
    }
}

// ------- out = ((pooled @ out_proj^T + bo) @ mlp^T + bm) -------
__global__ __launch_bounds__(256) void k5_head(
    const float* __restrict__ pooled, const float* __restrict__ wo, const float* __restrict__ bo,
    const float* __restrict__ wm, const float* __restrict__ bm, float* __restrict__ out) {
    __shared__ float pc[DH];
    __shared__ float t1[DH];
    const int b = blockIdx.x, tid = threadIdx.x;
    pc[tid] = pooled[(size_t)b * DH + tid];
    __syncthreads();
    float acc = bo[tid];
    for (int d = 0; d < DH; ++d) acc += pc[d] * wo[(size_t)tid * DH + d];
    t1[tid] = acc;
    __syncthreads();
    float acc2 = bm[tid];
    for (int e2 = 0; e2 < DH; ++e2) acc2 += t1[e2] * wm[(size_t)tid * DH + e2];
    out[(size_t)b * DH + tid] = acc2;
}

extern "C" void kernel_launch(void* const* d_in, const int* in_sizes, int n_in,
                              void* d_out, int out_size, void* d_ws, size_t ws_size,
                              hipStream_t stream) {
    (void)in_sizes; (void)n_in; (void)out_size; (void)ws_size;
    const float* x     = (const float*)d_in[0];
    const int*   src   = (const int*)d_in[1];
    const int*   dst   = (const int*)d_in[2];
    const int*   etype = (const int*)d_in[3];
    const float* wrel  = (const float*)d_in[4];
    const float* wloop = (const float*)d_in[5];
    const float* brel  = (const float*)d_in[6];
    const float* wq    = (const float*)d_in[7];
    const float* bq    = (const float*)d_in[8];
    const float* wo    = (const float*)d_in[9];
    const float* bo    = (const float*)d_in[10];
    const float* wm    = (const float*)d_in[11];
    const float* bm    = (const float*)d_in[12];
    float* out = (float*)d_out;

    char* W = (char*)d_ws;
    float* h      = (float*)W;                          // 38400*256*4 = 39,321,600
    u16*   xb     = (u16*)(W + 39321600ull);            // 38400*768*2 = 58,982,400 (aliased by qkvb)
    u16*   qkvb   = xb;                                 // k3m writes after xb is dead
    u16*   hb     = (u16*)(W + 39321600ull + 58982400ull);              // 19,660,800
    uint4* wrb    = (uint4*)(W + 39321600ull + 58982400ull + 19660800ull);  // 10,223,616
    uint4* wlb    = (uint4*)((char*)wrb + 10223616ull);                 // 393,216
    uint4* wqb    = (uint4*)((char*)wlb + 393216ull);                   // 393,216
    float* pooled = (float*)((char*)wqb + 393216ull);                   // 131,072
    int*   ibase  = (int*)((char*)pooled + 131072ull);
    int*   cnt    = ibase;
    int*   cur    = ibase + 32;
    int*   off    = ibase + 64;
    int*   list   = ibase + 128;                         // 38400 ints

    k0_zero<<<1, 64, 0, stream>>>(cnt, cur);
    k0_count<<<150, 256, 0, stream>>>(etype, cnt);
    k0_scan<<<1, 64, 0, stream>>>(cnt, off);
    k0_fill<<<150, 256, 0, stream>>>(etype, off, cur, list);

    c_cast8<<<14400, 256, 0, stream>>>((const float4*)x, (uint4*)xb, 3686400);
    c_cast_w<<<2688, 256, 0, stream>>>(wrel, wloop, wq, wrb, wlb, wqb);

    k1m<<<dim3(600, 2), 256, 0, stream>>>((const uint4*)xb, wlb, brel, h);
    k2m<<<dim3(600, 26, 2), 256, 0, stream>>>((const uint4*)xb, wrb, src, dst, cnt, off, list, h);
    c_cast8<<<4800, 256, 0, stream>>>((const float4*)h, (uint4*)hb, 1228800);
    k3m<<<dim3(600, 6), 256, 0, stream>>>((const uint4*)hb, wqb, bq, qkvb);
    k4_attn<<<BB * NHEADS, 256, 0, stream>>>(qkvb, pooled);
    k5_head<<<BB, 256, 0, stream>>>(pooled, wo, bo, wm, bm, out);
}